// Round 1
// baseline (200.675 us; speedup 1.0000x reference)
//
#include <hip/hip_runtime.h>
#include <hip/hip_bf16.h>

#define H 64

// Kernel 1: per-node projections.
//   A[n][c] = sum_k h[n][k] * W1[k][c]        (top half of W1: rows 0..63)
//   B[n][c] = sum_k h[n][k] * W1[64+k][c]     (bottom half: rows 64..127)
// Block = 256 threads = 4 nodes (one wave per node: lanes are the 64 output
// channels c). h row is staged in LDS and broadcast (same-address -> free).
// W1 reads are coalesced across c and L1-resident (32 KB = whole W1).
__global__ void __launch_bounds__(256)
node_proj_kernel(const float* __restrict__ h,
                 const float* __restrict__ W1,
                 float* __restrict__ A,
                 float* __restrict__ B,
                 int n_nodes) {
    __shared__ float sh[4][H];
    const int t = threadIdx.x;
    const int ln = t >> 6;   // local node 0..3 (== wave id)
    const int c  = t & 63;   // output channel == lane
    const int node = blockIdx.x * 4 + ln;

    if (node < n_nodes) sh[ln][c] = h[(size_t)node * H + c];
    __syncthreads();
    if (node >= n_nodes) return;

    float accA = 0.f, accB = 0.f;
#pragma unroll
    for (int k = 0; k < H; ++k) {
        const float hv = sh[ln][k];                 // wave-uniform broadcast
        accA = fmaf(hv, W1[k * H + c], accA);       // coalesced across lanes
        accB = fmaf(hv, W1[(k + H) * H + c], accB);
    }
    A[(size_t)node * H + c] = accA;
    B[(size_t)node * H + c] = accB;
}

// Kernel 2: per-edge score.
//   hid = relu(A[src] + B[dst] + b1)   (64 floats)
//   score = hid . W2 + b2 ;  label = score > 0 ? 1 : 0
// 16 lanes per edge, each lane owns one float4 slice (16 lanes x 16 B = full
// 256 B row, coalesced within the group). Dot product reduced with 4
// __shfl_xor steps (masks 1,2,4,8 stay inside the 16-lane group).
// Each thread handles 4 edges to amortize the b1/W2 register preload.
__global__ void __launch_bounds__(256)
edge_score_kernel(const float* __restrict__ A,
                  const float* __restrict__ B,
                  const int* __restrict__ src,
                  const int* __restrict__ dst,
                  const float* __restrict__ b1,
                  const float* __restrict__ W2,
                  const float* __restrict__ b2,
                  float* __restrict__ score_out,
                  float* __restrict__ label_out,
                  int n_edges) {
    const int t = threadIdx.x;
    const int sub = t & 15;          // position within edge group (0..15)
    const int group = t >> 4;        // edge group within block (0..15)

    const float4 b1v = ((const float4*)b1)[sub];
    const float4 w2v = ((const float4*)W2)[sub];
    const float b2s = b2[0];

    const int e_base = blockIdx.x * 64 + group;   // 64 edges per block
#pragma unroll
    for (int i = 0; i < 4; ++i) {
        const int e = e_base + i * 16;
        if (e < n_edges) {
            const int s = src[e];
            const int d = dst[e];
            const float4 a4 = ((const float4*)(A + (size_t)s * H))[sub];
            const float4 c4 = ((const float4*)(B + (size_t)d * H))[sub];
            const float h0 = fmaxf(a4.x + c4.x + b1v.x, 0.f);
            const float h1 = fmaxf(a4.y + c4.y + b1v.y, 0.f);
            const float h2 = fmaxf(a4.z + c4.z + b1v.z, 0.f);
            const float h3 = fmaxf(a4.w + c4.w + b1v.w, 0.f);
            float p = h0 * w2v.x + h1 * w2v.y + h2 * w2v.z + h3 * w2v.w;
            p += __shfl_xor(p, 1);
            p += __shfl_xor(p, 2);
            p += __shfl_xor(p, 4);
            p += __shfl_xor(p, 8);
            if (sub == 0) {
                const float sc = p + b2s;
                score_out[e] = sc;
                // label = round(sigmoid(sc)); sigmoid(0)=0.5 rounds-to-even -> 0,
                // so strict > matches jnp.round.
                label_out[e] = sc > 0.f ? 1.f : 0.f;
            }
        }
    }
}

extern "C" void kernel_launch(void* const* d_in, const int* in_sizes, int n_in,
                              void* d_out, int out_size, void* d_ws, size_t ws_size,
                              hipStream_t stream) {
    // Inputs (setup_inputs order): h, src, dst, W1, b1, W2, b2
    const float* h   = (const float*)d_in[0];
    const int*   src = (const int*)  d_in[1];
    const int*   dst = (const int*)  d_in[2];
    const float* W1  = (const float*)d_in[3];
    const float* b1  = (const float*)d_in[4];
    const float* W2  = (const float*)d_in[5];
    const float* b2  = (const float*)d_in[6];

    const int n_nodes = in_sizes[0] / H;
    const int n_edges = in_sizes[1];

    // Workspace layout: A [n_nodes x 64] fp32, then B [n_nodes x 64] fp32.
    float* A = (float*)d_ws;
    float* B = A + (size_t)n_nodes * H;

    float* score_out = (float*)d_out;            // first n_edges floats
    float* label_out = score_out + n_edges;      // next n_edges floats

    {
        const int blocks = (n_nodes + 3) / 4;
        node_proj_kernel<<<blocks, 256, 0, stream>>>(h, W1, A, B, n_nodes);
    }
    {
        const int blocks = (n_edges + 63) / 64;
        edge_score_kernel<<<blocks, 256, 0, stream>>>(A, B, src, dst, b1, W2, b2,
                                                      score_out, label_out, n_edges);
    }
}

// Round 2
// 172.689 us; speedup vs baseline: 1.1621x; 1.1621x over previous
//
#include <hip/hip_runtime.h>
#include <hip/hip_bf16.h>

#define H 64
#define NPB 64   // nodes per block (node_proj)
#define EPB 128  // edges per block (edge_score)

// Kernel 1: per-node projections A = h @ W1[:64], B = h @ W1[64:].
// Block = 256 threads = 4 waves. Lane owns output channel c = lane.
// W1 column c cached in 128 VGPRs (wA[64], wB[64]); h tile (64 rows, 16 KB)
// staged in LDS and read via broadcast float4 (same-address -> conflict-free).
// 128 FMAs per 16 LDS reads -> VALU-bound (~5 us chip-wide).
__global__ void __launch_bounds__(256)
node_proj_kernel(const float* __restrict__ h,
                 const float* __restrict__ W1,
                 float* __restrict__ A,
                 float* __restrict__ B,
                 int n_nodes) {
    __shared__ float sh[NPB * H];  // 16 KB
    const int t = threadIdx.x;
    const int c = t & 63;          // channel == lane
    const int w = t >> 6;          // wave 0..3
    const int base = blockIdx.x * NPB;

    // Stage h tile: 64 rows x 256 B = 1024 float4, 4 per thread, coalesced.
    {
        const float4* hg = (const float4*)(h + (size_t)base * H);
        float4* shv = (float4*)sh;
#pragma unroll
        for (int i = 0; i < 4; ++i) {
            const int idx = t + i * 256;            // float4 index in tile
            const int node = base + (idx >> 4);     // 16 float4 per row
            if (node < n_nodes) shv[idx] = hg[idx];
        }
    }

    // Register-cache W1 column c (top half -> wA, bottom half -> wB).
    float wA[64], wB[64];
#pragma unroll
    for (int k = 0; k < 64; ++k) {
        wA[k] = W1[k * H + c];
        wB[k] = W1[(k + 64) * H + c];
    }
    __syncthreads();

    // Each wave computes 16 nodes, 2 at a time for ILP.
#pragma unroll 1
    for (int n0 = 0; n0 < 8; ++n0) {
        const int nl = w * 16 + n0 * 2;
        const int node = base + nl;
        if (node >= n_nodes) break;                 // wave-uniform
        const bool two = (node + 1) < n_nodes;
        const float4* hr0 = (const float4*)(sh + nl * H);
        const float4* hr1 = (const float4*)(sh + (nl + 1) * H);
        float a0 = 0.f, b0 = 0.f, a1 = 0.f, b1acc = 0.f;
#pragma unroll
        for (int kk = 0; kk < 16; ++kk) {
            const float4 h0 = hr0[kk];
            const float4 h1 = hr1[kk];
            a0 = fmaf(h0.x, wA[4 * kk + 0], a0);
            a0 = fmaf(h0.y, wA[4 * kk + 1], a0);
            a0 = fmaf(h0.z, wA[4 * kk + 2], a0);
            a0 = fmaf(h0.w, wA[4 * kk + 3], a0);
            b0 = fmaf(h0.x, wB[4 * kk + 0], b0);
            b0 = fmaf(h0.y, wB[4 * kk + 1], b0);
            b0 = fmaf(h0.z, wB[4 * kk + 2], b0);
            b0 = fmaf(h0.w, wB[4 * kk + 3], b0);
            a1 = fmaf(h1.x, wA[4 * kk + 0], a1);
            a1 = fmaf(h1.y, wA[4 * kk + 1], a1);
            a1 = fmaf(h1.z, wA[4 * kk + 2], a1);
            a1 = fmaf(h1.w, wA[4 * kk + 3], a1);
            b1acc = fmaf(h1.x, wB[4 * kk + 0], b1acc);
            b1acc = fmaf(h1.y, wB[4 * kk + 1], b1acc);
            b1acc = fmaf(h1.z, wB[4 * kk + 2], b1acc);
            b1acc = fmaf(h1.w, wB[4 * kk + 3], b1acc);
        }
        A[(size_t)node * H + c] = a0;
        B[(size_t)node * H + c] = b0;
        if (two) {
            A[(size_t)(node + 1) * H + c] = a1;
            B[(size_t)(node + 1) * H + c] = b1acc;
        }
    }
}

// Kernel 2: per-edge score = relu(A[src]+B[dst]+b1) . W2 + b2.
// 16 lanes per edge (lane owns one float4 slice = 256 B coalesced row read).
// 8 edges per thread with ALL index loads hoisted, then ALL 16 row gathers
// issued back-to-back -> 16 outstanding gathers/thread (vs 2 before) to hide
// IF$/L2 latency. Reduction: 4 x __shfl_xor within the 16-lane group.
__global__ void __launch_bounds__(256)
edge_score_kernel(const float* __restrict__ A,
                  const float* __restrict__ B,
                  const int* __restrict__ src,
                  const int* __restrict__ dst,
                  const float* __restrict__ b1,
                  const float* __restrict__ W2,
                  const float* __restrict__ b2,
                  float* __restrict__ score_out,
                  float* __restrict__ label_out,
                  int n_edges) {
    const int t = threadIdx.x;
    const int sub = t & 15;
    const int group = t >> 4;   // 0..15

    const float4 b1v = ((const float4*)b1)[sub];
    const float4 w2v = ((const float4*)W2)[sub];
    const float b2s = b2[0];

    const int e0 = blockIdx.x * EPB + group;

    int ec[8], s[8], d[8];
#pragma unroll
    for (int i = 0; i < 8; ++i) {
        const int e = e0 + i * 16;
        ec[i] = e < n_edges ? e : (n_edges - 1);    // clamp: loads stay valid
    }
#pragma unroll
    for (int i = 0; i < 8; ++i) { s[i] = src[ec[i]]; d[i] = dst[ec[i]]; }

    float4 a4[8], c4[8];
#pragma unroll
    for (int i = 0; i < 8; ++i)
        a4[i] = ((const float4*)(A + (size_t)s[i] * H))[sub];
#pragma unroll
    for (int i = 0; i < 8; ++i)
        c4[i] = ((const float4*)(B + (size_t)d[i] * H))[sub];

#pragma unroll
    for (int i = 0; i < 8; ++i) {
        const float h0 = fmaxf(a4[i].x + c4[i].x + b1v.x, 0.f);
        const float h1 = fmaxf(a4[i].y + c4[i].y + b1v.y, 0.f);
        const float h2 = fmaxf(a4[i].z + c4[i].z + b1v.z, 0.f);
        const float h3 = fmaxf(a4[i].w + c4[i].w + b1v.w, 0.f);
        float p = h0 * w2v.x + h1 * w2v.y + h2 * w2v.z + h3 * w2v.w;
        p += __shfl_xor(p, 1);
        p += __shfl_xor(p, 2);
        p += __shfl_xor(p, 4);
        p += __shfl_xor(p, 8);
        const int e = e0 + i * 16;
        if (sub == 0 && e < n_edges) {
            const float sc = p + b2s;
            score_out[e] = sc;
            // label = round(sigmoid(sc)); 0.5 rounds-to-even -> 0, so strict >.
            label_out[e] = sc > 0.f ? 1.f : 0.f;
        }
    }
}

extern "C" void kernel_launch(void* const* d_in, const int* in_sizes, int n_in,
                              void* d_out, int out_size, void* d_ws, size_t ws_size,
                              hipStream_t stream) {
    // Inputs (setup_inputs order): h, src, dst, W1, b1, W2, b2
    const float* h   = (const float*)d_in[0];
    const int*   src = (const int*)  d_in[1];
    const int*   dst = (const int*)  d_in[2];
    const float* W1  = (const float*)d_in[3];
    const float* b1  = (const float*)d_in[4];
    const float* W2  = (const float*)d_in[5];
    const float* b2  = (const float*)d_in[6];

    const int n_nodes = in_sizes[0] / H;
    const int n_edges = in_sizes[1];

    // Workspace: A [n_nodes x 64] fp32, then B [n_nodes x 64] fp32 (25.6 MB).
    float* A = (float*)d_ws;
    float* B = A + (size_t)n_nodes * H;

    float* score_out = (float*)d_out;
    float* label_out = score_out + n_edges;

    {
        const int blocks = (n_nodes + NPB - 1) / NPB;
        node_proj_kernel<<<blocks, 256, 0, stream>>>(h, W1, A, B, n_nodes);
    }
    {
        const int blocks = (n_edges + EPB - 1) / EPB;
        edge_score_kernel<<<blocks, 256, 0, stream>>>(A, B, src, dst, b1, W2, b2,
                                                      score_out, label_out, n_edges);
    }
}

// Round 3
// 147.035 us; speedup vs baseline: 1.3648x; 1.1745x over previous
//
#include <hip/hip_runtime.h>
#include <hip/hip_bf16.h>

#define H 64
#define NPB 64        // nodes per block (node_proj)
#define EPB 128       // edges per block (edge_score)
#define FB_THRESH 0.015f  // |score| below this -> exact fp32 recompute.
// bf16-path score noise is <= ~1.2e-3 (12 sigma), so the 0.015 classification
// margin is safe; ~1-2% of edges take the fp32 rescue path.

__device__ __forceinline__ unsigned short f2bf(float f) {
    unsigned u = __float_as_uint(f);
    unsigned r = (u + 0x7fffu + ((u >> 16) & 1u)) >> 16;  // RNE
    return (unsigned short)r;
}
__device__ __forceinline__ float bf_lo(unsigned w) { return __uint_as_float(w << 16); }
__device__ __forceinline__ float bf_hi(unsigned w) { return __uint_as_float(w & 0xffff0000u); }

// Kernel 1: per-node projections A = h @ W1[:64], B = h @ W1[64:].
// Same structure as R2 (W1 column register-cached, h tile in LDS, 2-node ILP)
// + additionally stores bf16 copies of A and B for the fast gather path.
__global__ void __launch_bounds__(256)
node_proj_kernel(const float* __restrict__ h,
                 const float* __restrict__ W1,
                 float* __restrict__ A32,
                 float* __restrict__ B32,
                 unsigned short* __restrict__ Abf,
                 unsigned short* __restrict__ Bbf,
                 int n_nodes) {
    __shared__ float sh[NPB * H];  // 16 KB
    const int t = threadIdx.x;
    const int c = t & 63;          // channel == lane
    const int w = t >> 6;          // wave 0..3
    const int base = blockIdx.x * NPB;

    {   // Stage h tile: 64 rows x 256 B, coalesced float4.
        const float4* hg = (const float4*)(h + (size_t)base * H);
        float4* shv = (float4*)sh;
#pragma unroll
        for (int i = 0; i < 4; ++i) {
            const int idx = t + i * 256;
            const int node = base + (idx >> 4);
            if (node < n_nodes) shv[idx] = hg[idx];
        }
    }

    float wA[64], wB[64];
#pragma unroll
    for (int k = 0; k < 64; ++k) {
        wA[k] = W1[k * H + c];
        wB[k] = W1[(k + 64) * H + c];
    }
    __syncthreads();

#pragma unroll 1
    for (int n0 = 0; n0 < 8; ++n0) {
        const int nl = w * 16 + n0 * 2;
        const int node = base + nl;
        if (node >= n_nodes) break;                 // wave-uniform
        const bool two = (node + 1) < n_nodes;
        const float4* hr0 = (const float4*)(sh + nl * H);
        const float4* hr1 = (const float4*)(sh + (nl + 1) * H);
        float a0 = 0.f, b0 = 0.f, a1 = 0.f, b1acc = 0.f;
#pragma unroll
        for (int kk = 0; kk < 16; ++kk) {
            const float4 h0 = hr0[kk];
            const float4 h1 = hr1[kk];
            a0 = fmaf(h0.x, wA[4 * kk + 0], a0);
            a0 = fmaf(h0.y, wA[4 * kk + 1], a0);
            a0 = fmaf(h0.z, wA[4 * kk + 2], a0);
            a0 = fmaf(h0.w, wA[4 * kk + 3], a0);
            b0 = fmaf(h0.x, wB[4 * kk + 0], b0);
            b0 = fmaf(h0.y, wB[4 * kk + 1], b0);
            b0 = fmaf(h0.z, wB[4 * kk + 2], b0);
            b0 = fmaf(h0.w, wB[4 * kk + 3], b0);
            a1 = fmaf(h1.x, wA[4 * kk + 0], a1);
            a1 = fmaf(h1.y, wA[4 * kk + 1], a1);
            a1 = fmaf(h1.z, wA[4 * kk + 2], a1);
            a1 = fmaf(h1.w, wA[4 * kk + 3], a1);
            b1acc = fmaf(h1.x, wB[4 * kk + 0], b1acc);
            b1acc = fmaf(h1.y, wB[4 * kk + 1], b1acc);
            b1acc = fmaf(h1.z, wB[4 * kk + 2], b1acc);
            b1acc = fmaf(h1.w, wB[4 * kk + 3], b1acc);
        }
        A32[(size_t)node * H + c] = a0;
        B32[(size_t)node * H + c] = b0;
        Abf[(size_t)node * H + c] = f2bf(a0);
        Bbf[(size_t)node * H + c] = f2bf(b0);
        if (two) {
            A32[(size_t)(node + 1) * H + c] = a1;
            B32[(size_t)(node + 1) * H + c] = b1acc;
            Abf[(size_t)(node + 1) * H + c] = f2bf(a1);
            Bbf[(size_t)(node + 1) * H + c] = f2bf(b1acc);
        }
    }
}

// Kernel 2: per-edge score = relu(A[src]+B[dst]+b1) . W2 + b2.
// Fast path gathers bf16 rows (128 B each, halves the L2-miss volume that is
// the measured 3.7 TB/s wall). Edges with |score| < FB_THRESH are recomputed
// from the fp32 rows with arithmetic bit-identical to the R2 kernel, so
// label sign decisions near zero are exact.
__global__ void __launch_bounds__(256)
edge_score_kernel(const unsigned short* __restrict__ Abf,
                  const unsigned short* __restrict__ Bbf,
                  const float* __restrict__ A32,
                  const float* __restrict__ B32,
                  const int* __restrict__ src,
                  const int* __restrict__ dst,
                  const float* __restrict__ b1,
                  const float* __restrict__ W2,
                  const float* __restrict__ b2,
                  float* __restrict__ score_out,
                  float* __restrict__ label_out,
                  int n_edges) {
    const int t = threadIdx.x;
    const int sub = t & 15;          // lane within 16-lane edge group
    const int group = t >> 4;

    const float4 b1v = ((const float4*)b1)[sub];
    const float4 w2v = ((const float4*)W2)[sub];
    const float b2s = b2[0];

    const int e0 = blockIdx.x * EPB + group;

    int ec[8], s[8], d[8];
#pragma unroll
    for (int i = 0; i < 8; ++i) {
        const int e = e0 + i * 16;
        ec[i] = e < n_edges ? e : (n_edges - 1);   // clamp keeps loads valid
    }
#pragma unroll
    for (int i = 0; i < 8; ++i) { s[i] = src[ec[i]]; d[i] = dst[ec[i]]; }

    // 16 bf16 row-gathers in flight (8 B per lane = 128 B per row, coalesced).
    uint2 av[8], cv[8];
#pragma unroll
    for (int i = 0; i < 8; ++i)
        av[i] = ((const uint2*)(Abf + (size_t)s[i] * H))[sub];
#pragma unroll
    for (int i = 0; i < 8; ++i)
        cv[i] = ((const uint2*)(Bbf + (size_t)d[i] * H))[sub];

#pragma unroll
    for (int i = 0; i < 8; ++i) {
        const float a0 = bf_lo(av[i].x), a1 = bf_hi(av[i].x);
        const float a2 = bf_lo(av[i].y), a3 = bf_hi(av[i].y);
        const float c0 = bf_lo(cv[i].x), c1 = bf_hi(cv[i].x);
        const float c2 = bf_lo(cv[i].y), c3 = bf_hi(cv[i].y);
        const float h0 = fmaxf(a0 + c0 + b1v.x, 0.f);
        const float h1 = fmaxf(a1 + c1 + b1v.y, 0.f);
        const float h2 = fmaxf(a2 + c2 + b1v.z, 0.f);
        const float h3 = fmaxf(a3 + c3 + b1v.w, 0.f);
        float p = h0 * w2v.x + h1 * w2v.y + h2 * w2v.z + h3 * w2v.w;
        p += __shfl_xor(p, 1);
        p += __shfl_xor(p, 2);
        p += __shfl_xor(p, 4);
        p += __shfl_xor(p, 8);
        float sc = p + b2s;   // identical in all 16 lanes of the group

        if (fabsf(sc) < FB_THRESH) {
            // Exact rescue: fp32 gather + R2's exact arithmetic. Branch is
            // uniform within the 16-lane group; shuffle partners (xor 1,2,4,8)
            // stay inside the active group.
            const float4 a4 = ((const float4*)(A32 + (size_t)s[i] * H))[sub];
            const float4 c4 = ((const float4*)(B32 + (size_t)d[i] * H))[sub];
            const float g0 = fmaxf(a4.x + c4.x + b1v.x, 0.f);
            const float g1 = fmaxf(a4.y + c4.y + b1v.y, 0.f);
            const float g2 = fmaxf(a4.z + c4.z + b1v.z, 0.f);
            const float g3 = fmaxf(a4.w + c4.w + b1v.w, 0.f);
            float q = g0 * w2v.x + g1 * w2v.y + g2 * w2v.z + g3 * w2v.w;
            q += __shfl_xor(q, 1);
            q += __shfl_xor(q, 2);
            q += __shfl_xor(q, 4);
            q += __shfl_xor(q, 8);
            sc = q + b2s;
        }

        const int e = e0 + i * 16;
        if (sub == 0 && e < n_edges) {
            score_out[e] = sc;
            // label = round(sigmoid(sc)); 0.5 rounds-to-even -> 0, so strict >.
            label_out[e] = sc > 0.f ? 1.f : 0.f;
        }
    }
}

extern "C" void kernel_launch(void* const* d_in, const int* in_sizes, int n_in,
                              void* d_out, int out_size, void* d_ws, size_t ws_size,
                              hipStream_t stream) {
    // Inputs (setup_inputs order): h, src, dst, W1, b1, W2, b2
    const float* h   = (const float*)d_in[0];
    const int*   src = (const int*)  d_in[1];
    const int*   dst = (const int*)  d_in[2];
    const float* W1  = (const float*)d_in[3];
    const float* b1  = (const float*)d_in[4];
    const float* W2  = (const float*)d_in[5];
    const float* b2  = (const float*)d_in[6];

    const int n_nodes = in_sizes[0] / H;
    const int n_edges = in_sizes[1];

    // Workspace: A32, B32 (fp32, 12.8 MB each), Abf, Bbf (bf16, 6.4 MB each).
    float* A32 = (float*)d_ws;
    float* B32 = A32 + (size_t)n_nodes * H;
    unsigned short* Abf = (unsigned short*)(B32 + (size_t)n_nodes * H);
    unsigned short* Bbf = Abf + (size_t)n_nodes * H;

    float* score_out = (float*)d_out;
    float* label_out = score_out + n_edges;

    {
        const int blocks = (n_nodes + NPB - 1) / NPB;
        node_proj_kernel<<<blocks, 256, 0, stream>>>(h, W1, A32, B32, Abf, Bbf,
                                                     n_nodes);
    }
    {
        const int blocks = (n_edges + EPB - 1) / EPB;
        edge_score_kernel<<<blocks, 256, 0, stream>>>(Abf, Bbf, A32, B32,
                                                      src, dst, b1, W2, b2,
                                                      score_out, label_out,
                                                      n_edges);
    }
}

// Round 4
// 139.152 us; speedup vs baseline: 1.4421x; 1.0567x over previous
//
#include <hip/hip_runtime.h>
#include <hip/hip_bf16.h>

#define H 64
#define NPB 64          // nodes per block (node_proj)
#define EPT 8           // edges per thread (edge_score)
#define FB_THRESH 0.008f  // |score| below this -> exact fp32 recompute.
// f16 fast-path score noise is ~1e-4 std, max ~1e-3 over 1.25M edges, so an
// 0.008 classification margin has ~8x safety; ~0.6% of edges take the rescue.

typedef _Float16 half2_t __attribute__((ext_vector_type(2)));

__device__ __forceinline__ half2_t h2relu(half2_t x) {
#if defined(__has_builtin) && __has_builtin(__builtin_elementwise_max)
    half2_t z = {(_Float16)0.f, (_Float16)0.f};
    return __builtin_elementwise_max(x, z);   // v_pk_max_f16
#else
    half2_t r;
    r.x = x.x > (_Float16)0.f ? x.x : (_Float16)0.f;
    r.y = x.y > (_Float16)0.f ? x.y : (_Float16)0.f;
    return r;
#endif
}

__device__ __forceinline__ float hdot2(half2_t a, half2_t b, float c) {
#if defined(__has_builtin) && __has_builtin(__builtin_amdgcn_fdot2)
    return __builtin_amdgcn_fdot2(a, b, c, false);  // v_dot2_f32_f16
#else
    return c + (float)a.x * (float)b.x + (float)a.y * (float)b.y;
#endif
}

// Kernel 1: per-node projections A = h @ W1[:64], B = h @ W1[64:].
// W1 column register-cached (128 VGPRs), h tile in LDS (broadcast reads),
// 2-node ILP. Stores fp32 (exact, for rescue) + f16 (fast gather path).
__global__ void __launch_bounds__(256)
node_proj_kernel(const float* __restrict__ h,
                 const float* __restrict__ W1,
                 float* __restrict__ A32,
                 float* __restrict__ B32,
                 _Float16* __restrict__ A16,
                 _Float16* __restrict__ B16,
                 int n_nodes) {
    __shared__ float sh[NPB * H];  // 16 KB
    const int t = threadIdx.x;
    const int c = t & 63;          // channel == lane
    const int w = t >> 6;          // wave 0..3
    const int base = blockIdx.x * NPB;

    {   // Stage h tile: 64 rows x 256 B, coalesced float4.
        const float4* hg = (const float4*)(h + (size_t)base * H);
        float4* shv = (float4*)sh;
#pragma unroll
        for (int i = 0; i < 4; ++i) {
            const int idx = t + i * 256;
            const int node = base + (idx >> 4);
            if (node < n_nodes) shv[idx] = hg[idx];
        }
    }

    float wA[64], wB[64];
#pragma unroll
    for (int k = 0; k < 64; ++k) {
        wA[k] = W1[k * H + c];
        wB[k] = W1[(k + 64) * H + c];
    }
    __syncthreads();

#pragma unroll 1
    for (int n0 = 0; n0 < 8; ++n0) {
        const int nl = w * 16 + n0 * 2;
        const int node = base + nl;
        if (node >= n_nodes) break;                 // wave-uniform
        const bool two = (node + 1) < n_nodes;
        const float4* hr0 = (const float4*)(sh + nl * H);
        const float4* hr1 = (const float4*)(sh + (nl + 1) * H);
        float a0 = 0.f, b0 = 0.f, a1 = 0.f, b1acc = 0.f;
#pragma unroll
        for (int kk = 0; kk < 16; ++kk) {
            const float4 h0 = hr0[kk];
            const float4 h1 = hr1[kk];
            a0 = fmaf(h0.x, wA[4 * kk + 0], a0);
            a0 = fmaf(h0.y, wA[4 * kk + 1], a0);
            a0 = fmaf(h0.z, wA[4 * kk + 2], a0);
            a0 = fmaf(h0.w, wA[4 * kk + 3], a0);
            b0 = fmaf(h0.x, wB[4 * kk + 0], b0);
            b0 = fmaf(h0.y, wB[4 * kk + 1], b0);
            b0 = fmaf(h0.z, wB[4 * kk + 2], b0);
            b0 = fmaf(h0.w, wB[4 * kk + 3], b0);
            a1 = fmaf(h1.x, wA[4 * kk + 0], a1);
            a1 = fmaf(h1.y, wA[4 * kk + 1], a1);
            a1 = fmaf(h1.z, wA[4 * kk + 2], a1);
            a1 = fmaf(h1.w, wA[4 * kk + 3], a1);
            b1acc = fmaf(h1.x, wB[4 * kk + 0], b1acc);
            b1acc = fmaf(h1.y, wB[4 * kk + 1], b1acc);
            b1acc = fmaf(h1.z, wB[4 * kk + 2], b1acc);
            b1acc = fmaf(h1.w, wB[4 * kk + 3], b1acc);
        }
        A32[(size_t)node * H + c] = a0;
        B32[(size_t)node * H + c] = b0;
        A16[(size_t)node * H + c] = (_Float16)a0;   // v_cvt_f16_f32 (RNE)
        B16[(size_t)node * H + c] = (_Float16)b0;
        if (two) {
            A32[(size_t)(node + 1) * H + c] = a1;
            B32[(size_t)(node + 1) * H + c] = b1acc;
            A16[(size_t)(node + 1) * H + c] = (_Float16)a1;
            B16[(size_t)(node + 1) * H + c] = (_Float16)b1acc;
        }
    }
}

// Kernel 2: per-edge score = relu(A[src]+B[dst]+b1) . W2 + b2.
// 8 lanes per edge; each lane gathers one 16 B dwordx4 slice (8 f16) of the
// 128 B f16 row. 8 edges/thread with all 16 gathers in flight. Math is packed
// f16 (pk_add, pk_max, dot2_f32_f16 with fp32 accumulate); reduction is 3
// __shfl_xor steps. Edges with |score| < FB_THRESH re-gather fp32 rows and
// recompute exactly, so label sign decisions are fp32-exact.
__global__ void __launch_bounds__(256)
edge_score_kernel(const _Float16* __restrict__ A16,
                  const _Float16* __restrict__ B16,
                  const float* __restrict__ A32,
                  const float* __restrict__ B32,
                  const int* __restrict__ src,
                  const int* __restrict__ dst,
                  const float* __restrict__ b1,
                  const float* __restrict__ W2,
                  const float* __restrict__ b2,
                  float* __restrict__ score_out,
                  float* __restrict__ label_out,
                  int n_edges) {
    const int t = threadIdx.x;
    const int sub = t & 7;           // lane within 8-lane edge group
    const int group = t >> 3;        // 0..31 within block

    // Lane sub owns channels [sub*8, sub*8+8).
    const float4 b1lo = ((const float4*)b1)[sub * 2 + 0];
    const float4 b1hi = ((const float4*)b1)[sub * 2 + 1];
    const float4 w2lo = ((const float4*)W2)[sub * 2 + 0];
    const float4 w2hi = ((const float4*)W2)[sub * 2 + 1];
    half2_t b1h[4], w2h[4];
    b1h[0] = (half2_t){(_Float16)b1lo.x, (_Float16)b1lo.y};
    b1h[1] = (half2_t){(_Float16)b1lo.z, (_Float16)b1lo.w};
    b1h[2] = (half2_t){(_Float16)b1hi.x, (_Float16)b1hi.y};
    b1h[3] = (half2_t){(_Float16)b1hi.z, (_Float16)b1hi.w};
    w2h[0] = (half2_t){(_Float16)w2lo.x, (_Float16)w2lo.y};
    w2h[1] = (half2_t){(_Float16)w2lo.z, (_Float16)w2lo.w};
    w2h[2] = (half2_t){(_Float16)w2hi.x, (_Float16)w2hi.y};
    w2h[3] = (half2_t){(_Float16)w2hi.z, (_Float16)w2hi.w};
    const float b2s = b2[0];

    const int e0 = blockIdx.x * (256 / 8 * EPT) + group;  // 256 edges/block

    int ec[EPT], s[EPT], d[EPT];
#pragma unroll
    for (int i = 0; i < EPT; ++i) {
        const int e = e0 + i * 32;
        ec[i] = e < n_edges ? e : (n_edges - 1);   // clamp keeps loads valid
    }
#pragma unroll
    for (int i = 0; i < EPT; ++i) { s[i] = src[ec[i]]; d[i] = dst[ec[i]]; }

    // 16 row-gathers in flight (16 B per lane, 128 B per row, coalesced).
    float4 av[EPT], cv[EPT];
#pragma unroll
    for (int i = 0; i < EPT; ++i)
        av[i] = ((const float4*)(A16 + (size_t)s[i] * H))[sub];
#pragma unroll
    for (int i = 0; i < EPT; ++i)
        cv[i] = ((const float4*)(B16 + (size_t)d[i] * H))[sub];

#pragma unroll
    for (int i = 0; i < EPT; ++i) {
        const half2_t* a2 = (const half2_t*)&av[i];
        const half2_t* c2 = (const half2_t*)&cv[i];
        float p = 0.f;
#pragma unroll
        for (int j = 0; j < 4; ++j) {
            half2_t hj = h2relu(a2[j] + c2[j] + b1h[j]);
            p = hdot2(hj, w2h[j], p);
        }
        p += __shfl_xor(p, 1);
        p += __shfl_xor(p, 2);
        p += __shfl_xor(p, 4);
        float sc = p + b2s;   // identical across the 8 lanes of the group

        if (fabsf(sc) < FB_THRESH) {
            // Exact fp32 rescue. Branch is uniform within the 8-lane group;
            // shuffle partners (xor 1,2,4) stay inside the active group.
            const float4 ra0 = ((const float4*)(A32 + (size_t)s[i] * H))[sub * 2 + 0];
            const float4 ra1 = ((const float4*)(A32 + (size_t)s[i] * H))[sub * 2 + 1];
            const float4 rb0 = ((const float4*)(B32 + (size_t)d[i] * H))[sub * 2 + 0];
            const float4 rb1 = ((const float4*)(B32 + (size_t)d[i] * H))[sub * 2 + 1];
            float q = 0.f;
            q += fmaxf(ra0.x + rb0.x + b1lo.x, 0.f) * w2lo.x;
            q += fmaxf(ra0.y + rb0.y + b1lo.y, 0.f) * w2lo.y;
            q += fmaxf(ra0.z + rb0.z + b1lo.z, 0.f) * w2lo.z;
            q += fmaxf(ra0.w + rb0.w + b1lo.w, 0.f) * w2lo.w;
            q += fmaxf(ra1.x + rb1.x + b1hi.x, 0.f) * w2hi.x;
            q += fmaxf(ra1.y + rb1.y + b1hi.y, 0.f) * w2hi.y;
            q += fmaxf(ra1.z + rb1.z + b1hi.z, 0.f) * w2hi.z;
            q += fmaxf(ra1.w + rb1.w + b1hi.w, 0.f) * w2hi.w;
            q += __shfl_xor(q, 1);
            q += __shfl_xor(q, 2);
            q += __shfl_xor(q, 4);
            sc = q + b2s;
        }

        const int e = e0 + i * 32;
        if (sub == 0 && e < n_edges) {
            score_out[e] = sc;
            // label = round(sigmoid(sc)); 0.5 rounds-to-even -> 0, so strict >.
            label_out[e] = sc > 0.f ? 1.f : 0.f;
        }
    }
}

extern "C" void kernel_launch(void* const* d_in, const int* in_sizes, int n_in,
                              void* d_out, int out_size, void* d_ws, size_t ws_size,
                              hipStream_t stream) {
    // Inputs (setup_inputs order): h, src, dst, W1, b1, W2, b2
    const float* h   = (const float*)d_in[0];
    const int*   src = (const int*)  d_in[1];
    const int*   dst = (const int*)  d_in[2];
    const float* W1  = (const float*)d_in[3];
    const float* b1  = (const float*)d_in[4];
    const float* W2  = (const float*)d_in[5];
    const float* b2  = (const float*)d_in[6];

    const int n_nodes = in_sizes[0] / H;
    const int n_edges = in_sizes[1];

    // Workspace: A32, B32 (fp32, 12.8 MB each), A16, B16 (f16, 6.4 MB each).
    float* A32 = (float*)d_ws;
    float* B32 = A32 + (size_t)n_nodes * H;
    _Float16* A16 = (_Float16*)(B32 + (size_t)n_nodes * H);
    _Float16* B16 = A16 + (size_t)n_nodes * H;

    float* score_out = (float*)d_out;
    float* label_out = score_out + n_edges;

    {
        const int blocks = (n_nodes + NPB - 1) / NPB;
        node_proj_kernel<<<blocks, 256, 0, stream>>>(h, W1, A32, B32, A16, B16,
                                                     n_nodes);
    }
    {
        const int epb = 256 / 8 * EPT;   // 256 edges per block
        const int blocks = (n_edges + epb - 1) / epb;
        edge_score_kernel<<<blocks, 256, 0, stream>>>(A16, B16, A32, B32,
                                                      src, dst, b1, W2, b2,
                                                      score_out, label_out,
                                                      n_edges);
    }
}